// Round 11
// baseline (54.350 us; speedup 1.0000x reference)
//
#include <hip/hip_runtime.h>
#include <stdint.h>

// ---------------------------------------------------------------------------
// GraphSAGE SampleAndAggregate — RNG VERIFIED (round 5, variant 5):
//   modern JAX: partitionable threefry, foldlike split, and randint's
//   INTERNAL k1,k2=split(key); col_i = (x0^x1)(tf(tf(key,(0,1)),(0,i))) & 127
// DO NOT change the RNG path.
// ---------------------------------------------------------------------------
#define N_NODES 100000
#define F_DIM   256
#define H_DIM   128
#define MAX_DEG 128
#define BATCH   512
#define S1N     25
#define S2N     10
#define NS1     (BATCH * S2N)   // 5120
#define NS2     (NS1 * S1N)     // 128000

__device__ __forceinline__ void tf2(uint32_t k0, uint32_t k1, uint32_t c0, uint32_t c1,
                                    uint32_t& o0, uint32_t& o1) {
  uint32_t ks0 = k0, ks1 = k1, ks2 = k0 ^ k1 ^ 0x1BD11BDAu;
  uint32_t x0 = c0 + ks0;
  uint32_t x1 = c1 + ks1;
#define TF_ROUND(r) { x0 += x1; x1 = (x1 << (r)) | (x1 >> (32 - (r))); x1 ^= x0; }
  TF_ROUND(13); TF_ROUND(15); TF_ROUND(26); TF_ROUND(6);
  x0 += ks1; x1 += ks2 + 1u;
  TF_ROUND(17); TF_ROUND(29); TF_ROUND(16); TF_ROUND(24);
  x0 += ks2; x1 += ks0 + 2u;
  TF_ROUND(13); TF_ROUND(15); TF_ROUND(26); TF_ROUND(6);
  x0 += ks0; x1 += ks1 + 3u;
  TF_ROUND(17); TF_ROUND(29); TF_ROUND(16); TF_ROUND(24);
  x0 += ks1; x1 += ks2 + 4u;
  TF_ROUND(13); TF_ROUND(15); TF_ROUND(26); TF_ROUND(6);
  x0 += ks2; x1 += ks0 + 5u;
#undef TF_ROUND
  o0 = x0; o1 = x1;
}

// col draw i of randint(subkey_idx, ..., 0, 128) under verified semantics
__device__ __forceinline__ uint32_t jax_col(int subkey_idx, uint32_t i) {
  uint32_t k0, k1, kk0, kk1, o0, o1;
  tf2(0u, 42u, 0u, (uint32_t)subkey_idx, k0, k1);  // foldlike split of key(42)
  tf2(k0, k1, 0u, 1u, kk0, kk1);                   // randint internal k2
  tf2(kk0, kk1, 0u, i, o0, o1);                    // lower_bits draw i
  return (o0 ^ o1) & (MAX_DEG - 1);
}

// ---------------------------------------------------------------------------
// K1 (fused sample + gather + layer-0 matmul for the 5120 h1 rows).
// Grid 640, block 512. Wave w (of 8) owns s1-row r0+w.
// Gather: ALL 26 1-KB row-loads issued into 26 distinct float4 regs, then a
// sched_barrier(0) fence, then the sum. This forces ~26 loads in flight per
// wave (the r9/r10 versions were register-minimized to ~1 by the compiler —
// VGPR_Count 20/32 — leaving HBM at 15% and the kernel latency-bound).
#define RMM 8
__global__ __launch_bounds__(512, 1) void k_gmm(const float* __restrict__ feat,
                                                const int* __restrict__ adj,
                                                const int* __restrict__ batch,
                                                const float* __restrict__ Ws,
                                                const float* __restrict__ Wn,
                                                float* __restrict__ Xself,
                                                float* __restrict__ h1out) {
  __shared__ int   nbr[RMM][26];    // [.][25] = self (s1)
  __shared__ float xl[2][512][4];   // 16 KB, transposed X tile
  const int tid = threadIdx.x;
  const int r0 = blockIdx.x * RMM;

  if (tid < RMM * 26) {
    int rr = tid / 26, t = tid % 26;
    int r = r0 + rr;
    uint32_t c0 = jax_col(0, (uint32_t)r);
    int s1 = adj[(size_t)batch[r / S2N] * MAX_DEG + c0];
    if (t < 25) {
      uint32_t col = jax_col(1, (uint32_t)(r * S1N + t));
      nbr[rr][t] = adj[(size_t)s1 * MAX_DEG + col];
    } else {
      nbr[rr][25] = s1;
    }
  }
  __syncthreads();

  // ---- gather: wave w -> row w; 26 loads forced in flight ----
  {
    const int w = tid >> 6, lane = tid & 63;
    const int k0 = lane * 4;

    int idx[26];
#pragma unroll
    for (int t = 0; t < 26; ++t)
      idx[t] = __builtin_amdgcn_readfirstlane(nbr[w][t]);

    float4 v[26];
#pragma unroll
    for (int t = 0; t < 26; ++t)
      v[t] = *reinterpret_cast<const float4*>(&feat[(size_t)idx[t] * F_DIM + k0]);
    // hard scheduling fence: no consumer may be hoisted above this point,
    // no load may be sunk below it -> all 26 stay in flight.
    __builtin_amdgcn_sched_barrier(0);

    float4 p0, p1, p2, p3, p4;
#define VADD(d, a, b) d.x = a.x + b.x; d.y = a.y + b.y; d.z = a.z + b.z; d.w = a.w + b.w
    p0 = v[0];  p1 = v[1];  p2 = v[2];  p3 = v[3];  p4 = v[4];
#pragma unroll
    for (int t = 5; t < 25; t += 5) {
      VADD(p0, p0, v[t + 0]); VADD(p1, p1, v[t + 1]); VADD(p2, p2, v[t + 2]);
      VADD(p3, p3, v[t + 3]); VADD(p4, p4, v[t + 4]);
    }
    float4 a;
    a.x = ((p0.x + p1.x) + (p2.x + p3.x)) + p4.x;
    a.y = ((p0.y + p1.y) + (p2.y + p3.y)) + p4.y;
    a.z = ((p0.z + p1.z) + (p2.z + p3.z)) + p4.z;
    a.w = ((p0.w + p1.w) + (p2.w + p3.w)) + p4.w;
#undef VADD
    const float4 s = v[25];

    // self half to global for k_tail's h0-neighbor-mean
    *reinterpret_cast<float4*>(&Xself[(size_t)(r0 + w) * 256 + k0]) = s;

    // transposed LDS store (one-time; write conflicts known & tolerated)
    const int G = w >> 2, rl = w & 3;
    const float inv = 1.f / (float)S1N;
    xl[G][k0 + 0][rl] = s.x;  xl[G][k0 + 1][rl] = s.y;
    xl[G][k0 + 2][rl] = s.z;  xl[G][k0 + 3][rl] = s.w;
    xl[G][256 + k0 + 0][rl] = a.x * inv; xl[G][256 + k0 + 1][rl] = a.y * inv;
    xl[G][256 + k0 + 2][rl] = a.z * inv; xl[G][256 + k0 + 3][rl] = a.w * inv;
  }
  __syncthreads();

  // ---- mm phase (same math as verified r6/r8; 4 rows per thread) ----
  const int j = tid & (H_DIM - 1);
  const int h = (tid >> 7) & 1;                    // 0: self@Ws, 1: mean@Wn
  const int q = tid >> 8;                          // row group: 0 -> 0-3, 1 -> 4-7
  const float* __restrict__ W = h ? Wn : Ws;
  float acc[4] = {0.f, 0.f, 0.f, 0.f};

#pragma unroll 4
  for (int k = 0; k < F_DIM; ++k) {
    float w = W[k * H_DIM + j];
    int kk = (h << 8) + k;
    float4 xa = *reinterpret_cast<const float4*>(&xl[q][kk][0]);
    acc[0] += xa.x * w; acc[1] += xa.y * w; acc[2] += xa.z * w; acc[3] += xa.w * w;
  }
#pragma unroll
  for (int i = 0; i < 4; ++i)
    h1out[(size_t)(r0 + q * 4 + i) * 256 + (h << 7) + j] = fmaxf(acc[i], 0.f);
}

// ---------------------------------------------------------------------------
// K2 (fused h0 + out): per batch row b (grid 512, 256 thr). Unchanged (verified).
__global__ __launch_bounds__(256) void k_tail(const float* __restrict__ feat,
                                              const int* __restrict__ batch,
                                              const float* __restrict__ Xself,
                                              const float* __restrict__ h1out,
                                              const float* __restrict__ Ws0,
                                              const float* __restrict__ Wn0,
                                              const float* __restrict__ Ws1,
                                              const float* __restrict__ Wn1,
                                              float* __restrict__ out) {
  __shared__ float sA[2][F_DIM];
  __shared__ float sB[2][F_DIM];
  __shared__ float red[4];
  const int tid = threadIdx.x;
  const int b = blockIdx.x;
  const int j = tid & (H_DIM - 1);
  const int h = tid >> 7;

  {
    float m = 0.f;
#pragma unroll
    for (int t = 0; t < S2N; ++t)
      m += Xself[(size_t)(b * S2N + t) * 256 + tid];
    sA[1][tid] = m / (float)S2N;
    sA[0][tid] = feat[(size_t)batch[b] * F_DIM + tid];
  }
  __syncthreads();

  const float* __restrict__ W0 = h ? Wn0 : Ws0;
  float a0 = 0.f;
#pragma unroll 4
  for (int k4 = 0; k4 < F_DIM / 4; ++k4) {
    float4 s4 = *reinterpret_cast<const float4*>(&sA[h][k4 * 4]);
    a0 += s4.x * W0[(k4 * 4 + 0) * H_DIM + j];
    a0 += s4.y * W0[(k4 * 4 + 1) * H_DIM + j];
    a0 += s4.z * W0[(k4 * 4 + 2) * H_DIM + j];
    a0 += s4.w * W0[(k4 * 4 + 3) * H_DIM + j];
  }
  a0 = fmaxf(a0, 0.f);

  sB[0][tid] = a0;
  {
    float m = 0.f;
#pragma unroll
    for (int t = 0; t < S2N; ++t)
      m += h1out[(size_t)(b * S2N + t) * 256 + tid];
    sB[1][tid] = m / (float)S2N;
  }
  __syncthreads();

  const float* __restrict__ W1 = h ? Wn1 : Ws1;
  float a1 = 0.f;
#pragma unroll 4
  for (int k4 = 0; k4 < F_DIM / 4; ++k4) {
    float4 s4 = *reinterpret_cast<const float4*>(&sB[h][k4 * 4]);
    a1 += s4.x * W1[(k4 * 4 + 0) * H_DIM + j];
    a1 += s4.y * W1[(k4 * 4 + 1) * H_DIM + j];
    a1 += s4.z * W1[(k4 * 4 + 2) * H_DIM + j];
    a1 += s4.w * W1[(k4 * 4 + 3) * H_DIM + j];
  }

  float s = a1 * a1;
#pragma unroll
  for (int off = 32; off > 0; off >>= 1) s += __shfl_xor(s, off);
  if ((tid & 63) == 0) red[tid >> 6] = s;
  __syncthreads();
  float tot = red[0] + red[1] + red[2] + red[3];
  float inv = 1.f / fmaxf(sqrtf(tot), 1e-12f);
  out[(size_t)b * 256 + tid] = a1 * inv;
}

// ---------------------------------------------------------------------------
extern "C" void kernel_launch(void* const* d_in, const int* in_sizes, int n_in,
                              void* d_out, int out_size, void* d_ws, size_t ws_size,
                              hipStream_t stream) {
  const float* feat  = (const float*)d_in[0];
  const int*   adj   = (const int*)d_in[1];
  const int*   batch = (const int*)d_in[2];
  const float* Ws0   = (const float*)d_in[3];
  const float* Wn0   = (const float*)d_in[4];
  const float* Ws1   = (const float*)d_in[5];
  const float* Wn1   = (const float*)d_in[6];
  float* out = (float*)d_out;

  char* ws = (char*)d_ws;
  float* Xself = (float*)(ws);                    // 5120*256*4 = 5.25 MB
  float* h1out = (float*)(ws + (8u << 20));       // 5120*256*4 = 5.25 MB

  k_gmm <<<NS1 / RMM, 512, 0, stream>>>(feat, adj, batch, Ws0, Wn0, Xself, h1out);
  k_tail<<<BATCH, 256, 0, stream>>>(feat, batch, Xself, h1out, Ws0, Wn0, Ws1, Wn1, out);
}